// Round 1
// baseline (117.476 us; speedup 1.0000x reference)
//
#include <hip/hip_runtime.h>

// Problem constants (fixed by setup_inputs in the reference):
//   pred_dT, gt_dT: (B=32, M=784, M=784, C=4) float32
//   Ms: (V=4,) int32, sum(Ms) == M
constexpr int B_ = 32;
constexpr int M_ = 784;
constexpr int C_ = 4;

constexpr int NBLK = 2048;   // memory-bound: ~8 blocks/CU, grid-stride rows
constexpr int NTHR = 256;

constexpr float ALPHA_T  = 0.5f;
constexpr float ALPHA_S  = 0.75f;
constexpr float ALPHA_TS = 0.5f;
constexpr float EPS      = 1e-8f;

// ---------------------------------------------------------------------------
// Kernel 1: block-stride over rows (b*M + i). Each thread handles pixels
// (b,i,j) with a float4 load per tensor (C=4 channels contiguous).
// Accumulate: all_t = sum d0^2+d1^2 ; all_s = sum d2^2+d3^2 ; intra_* same
// restricted to view(i)==view(j). One float4 partial per block -> d_ws.
// ---------------------------------------------------------------------------
__global__ __launch_bounds__(NTHR) void pose_loss_partial_kernel(
    const float* __restrict__ pred, const float* __restrict__ gt,
    const int* __restrict__ Ms, float4* __restrict__ partials)
{
    // View boundaries from Ms (V=4): view(i) = #cumsums <= i
    const int cum0 = Ms[0];
    const int cum1 = cum0 + Ms[1];
    const int cum2 = cum1 + Ms[2];

    float all_t = 0.f, all_s = 0.f, intra_t = 0.f, intra_s = 0.f;

    const int R = B_ * M_;
    for (int row = blockIdx.x; row < R; row += gridDim.x) {
        const int i  = row % M_;
        const int vi = (i >= cum0) + (i >= cum1) + (i >= cum2);
        const float4* __restrict__ prow =
            reinterpret_cast<const float4*>(pred + (size_t)row * (M_ * C_));
        const float4* __restrict__ grow =
            reinterpret_cast<const float4*>(gt   + (size_t)row * (M_ * C_));
        for (int j = threadIdx.x; j < M_; j += NTHR) {
            const float4 p = prow[j];
            const float4 g = grow[j];
            const float d0 = p.x - g.x;
            const float d1 = p.y - g.y;
            const float d2 = p.z - g.z;
            const float d3 = p.w - g.w;
            const float t = d0 * d0 + d1 * d1;
            const float s = d2 * d2 + d3 * d3;
            all_t += t;
            all_s += s;
            const int vj = (j >= cum0) + (j >= cum1) + (j >= cum2);
            if (vi == vj) { intra_t += t; intra_s += s; }
        }
    }

    // Wave (64-lane) shuffle reduction, then LDS across the 4 waves.
    float v0 = all_t, v1 = all_s, v2 = intra_t, v3 = intra_s;
    #pragma unroll
    for (int off = 32; off > 0; off >>= 1) {
        v0 += __shfl_down(v0, off, 64);
        v1 += __shfl_down(v1, off, 64);
        v2 += __shfl_down(v2, off, 64);
        v3 += __shfl_down(v3, off, 64);
    }

    __shared__ float4 sm[NTHR / 64];
    const int lane = threadIdx.x & 63;
    const int wid  = threadIdx.x >> 6;
    if (lane == 0) sm[wid] = make_float4(v0, v1, v2, v3);
    __syncthreads();

    if (threadIdx.x == 0) {
        float4 acc = sm[0];
        #pragma unroll
        for (int w = 1; w < NTHR / 64; ++w) {
            acc.x += sm[w].x; acc.y += sm[w].y;
            acc.z += sm[w].z; acc.w += sm[w].w;
        }
        partials[blockIdx.x] = acc;
    }
}

// ---------------------------------------------------------------------------
// Kernel 2: single block. Deterministic reduction of NBLK partials, then the
// scalar loss arithmetic, writing the 7-element output vector.
// ---------------------------------------------------------------------------
__global__ __launch_bounds__(NTHR) void pose_loss_final_kernel(
    const float4* __restrict__ partials, const int* __restrict__ Ms,
    float* __restrict__ out)
{
    float v0 = 0.f, v1 = 0.f, v2 = 0.f, v3 = 0.f;
    for (int p = threadIdx.x; p < NBLK; p += NTHR) {
        const float4 q = partials[p];
        v0 += q.x; v1 += q.y; v2 += q.z; v3 += q.w;
    }
    #pragma unroll
    for (int off = 32; off > 0; off >>= 1) {
        v0 += __shfl_down(v0, off, 64);
        v1 += __shfl_down(v1, off, 64);
        v2 += __shfl_down(v2, off, 64);
        v3 += __shfl_down(v3, off, 64);
    }
    __shared__ float4 sm[NTHR / 64];
    const int lane = threadIdx.x & 63;
    const int wid  = threadIdx.x >> 6;
    if (lane == 0) sm[wid] = make_float4(v0, v1, v2, v3);
    __syncthreads();

    if (threadIdx.x == 0) {
        float4 acc = sm[0];
        #pragma unroll
        for (int w = 1; w < NTHR / 64; ++w) {
            acc.x += sm[w].x; acc.y += sm[w].y;
            acc.z += sm[w].z; acc.w += sm[w].w;
        }
        const float total_all_t   = acc.x;
        const float total_all_s   = acc.y;
        const float total_intra_t = acc.z;
        const float total_intra_s = acc.w;
        const float total_inter_t = total_all_t - total_intra_t;
        const float total_inter_s = total_all_s - total_intra_s;

        int sum_Ms_sq = 0;
        #pragma unroll
        for (int v = 0; v < 4; ++v) sum_Ms_sq += Ms[v] * Ms[v];
        const float diag_count    = (float)((long long)sum_Ms_sq * B_);
        const float offdiag_count = (float)(((long long)M_ * M_ - sum_Ms_sq) * B_);

        const float li_t = (diag_count    > EPS) ? total_intra_t / diag_count    : 0.f;
        const float le_t = (offdiag_count > EPS) ? total_inter_t / offdiag_count : 0.f;
        const float li_s = (diag_count    > EPS) ? total_intra_s / diag_count    : 0.f;
        const float le_s = (offdiag_count > EPS) ? total_inter_s / offdiag_count : 0.f;

        const float loss_t = ALPHA_T  * le_t + (1.f - ALPHA_T)  * li_t;
        const float loss_s = ALPHA_S  * le_s + (1.f - ALPHA_S)  * li_s;
        const float loss   = ALPHA_TS * loss_t + (1.f - ALPHA_TS) * loss_s;

        out[0] = li_t;
        out[1] = le_t;
        out[2] = li_s;
        out[3] = le_s;
        out[4] = loss_t;
        out[5] = loss_s;
        out[6] = loss;
    }
}

extern "C" void kernel_launch(void* const* d_in, const int* in_sizes, int n_in,
                              void* d_out, int out_size, void* d_ws, size_t ws_size,
                              hipStream_t stream) {
    const float* pred = (const float*)d_in[0];
    const float* gt   = (const float*)d_in[1];
    const int*   Ms   = (const int*)d_in[2];
    float*       out  = (float*)d_out;
    float4*      partials = (float4*)d_ws;   // NBLK * 16 bytes = 32 KB

    pose_loss_partial_kernel<<<NBLK, NTHR, 0, stream>>>(pred, gt, Ms, partials);
    pose_loss_final_kernel<<<1, NTHR, 0, stream>>>(partials, Ms, out);
}

// Round 2
// 112.966 us; speedup vs baseline: 1.0399x; 1.0399x over previous
//
#include <hip/hip_runtime.h>

// Problem constants (fixed by setup_inputs in the reference):
//   pred_dT, gt_dT: (B=32, M=784, M=784, C=4) float32
//   Ms: (V=4,) int32, sum(Ms) == M
constexpr int B_ = 32;
constexpr int M_ = 784;

constexpr int NBLK = 1792;            // 7 blocks/CU; stride divides work into
constexpr int NTHR = 256;             // 42 full iterations + one 87.5% tail
constexpr int TOTAL  = B_ * M_ * M_;  // 19,668,992 float4 pixels per tensor
constexpr int STRIDE = NBLK * NTHR;   // 458,752
constexpr int KFULL  = TOTAL / STRIDE; // 42 (compile-time constant)

constexpr float ALPHA_T  = 0.5f;
constexpr float ALPHA_S  = 0.75f;
constexpr float ALPHA_TS = 0.5f;
constexpr float EPS      = 1e-8f;

// ---------------------------------------------------------------------------
// Kernel 1: flat grid-stride over all (b,i,j) pixels. One float4 per tensor
// per thread-iteration (C=4 channels contiguous). Accumulate 4 sums:
// all_t, all_s, intra_t, intra_s (intra := view(i)==view(j)).
// One float4 partial per block -> d_ws.
// ---------------------------------------------------------------------------
__global__ __launch_bounds__(NTHR) void pose_loss_partial_kernel(
    const float4* __restrict__ pred, const float4* __restrict__ gt,
    const int* __restrict__ Ms, float4* __restrict__ partials)
{
    const int cum0 = Ms[0];
    const int cum1 = cum0 + Ms[1];
    const int cum2 = cum1 + Ms[2];

    float all_t = 0.f, all_s = 0.f, intra_t = 0.f, intra_s = 0.f;

    auto body = [&](int idx) {
        const float4 p = pred[idx];
        const float4 g = gt[idx];
        const float d0 = p.x - g.x;
        const float d1 = p.y - g.y;
        const float d2 = p.z - g.z;
        const float d3 = p.w - g.w;
        const float t = d0 * d0 + d1 * d1;
        const float s = d2 * d2 + d3 * d3;
        all_t += t;
        all_s += s;
        const int q = idx / M_;        // magic-mul div (M_ constexpr)
        const int j = idx - q * M_;
        const int i = q - (q / M_) * M_;
        const int vi = (i >= cum0) + (i >= cum1) + (i >= cum2);
        const int vj = (j >= cum0) + (j >= cum1) + (j >= cum2);
        if (vi == vj) { intra_t += t; intra_s += s; }
    };

    int idx = blockIdx.x * NTHR + threadIdx.x;
    #pragma unroll 2
    for (int k = 0; k < KFULL; ++k, idx += STRIDE) {
        body(idx);
    }
    if (idx < TOTAL) {   // single 87.5%-active tail iteration
        body(idx);
    }

    // Wave (64-lane) shuffle reduction, then LDS across the 4 waves.
    float v0 = all_t, v1 = all_s, v2 = intra_t, v3 = intra_s;
    #pragma unroll
    for (int off = 32; off > 0; off >>= 1) {
        v0 += __shfl_down(v0, off, 64);
        v1 += __shfl_down(v1, off, 64);
        v2 += __shfl_down(v2, off, 64);
        v3 += __shfl_down(v3, off, 64);
    }

    __shared__ float4 sm[NTHR / 64];
    const int lane = threadIdx.x & 63;
    const int wid  = threadIdx.x >> 6;
    if (lane == 0) sm[wid] = make_float4(v0, v1, v2, v3);
    __syncthreads();

    if (threadIdx.x == 0) {
        float4 acc = sm[0];
        #pragma unroll
        for (int w = 1; w < NTHR / 64; ++w) {
            acc.x += sm[w].x; acc.y += sm[w].y;
            acc.z += sm[w].z; acc.w += sm[w].w;
        }
        partials[blockIdx.x] = acc;
    }
}

// ---------------------------------------------------------------------------
// Kernel 2: single block. Deterministic reduction of NBLK partials, then the
// scalar loss arithmetic, writing the 7-element output vector.
// ---------------------------------------------------------------------------
__global__ __launch_bounds__(NTHR) void pose_loss_final_kernel(
    const float4* __restrict__ partials, const int* __restrict__ Ms,
    float* __restrict__ out)
{
    float v0 = 0.f, v1 = 0.f, v2 = 0.f, v3 = 0.f;
    for (int p = threadIdx.x; p < NBLK; p += NTHR) {
        const float4 q = partials[p];
        v0 += q.x; v1 += q.y; v2 += q.z; v3 += q.w;
    }
    #pragma unroll
    for (int off = 32; off > 0; off >>= 1) {
        v0 += __shfl_down(v0, off, 64);
        v1 += __shfl_down(v1, off, 64);
        v2 += __shfl_down(v2, off, 64);
        v3 += __shfl_down(v3, off, 64);
    }
    __shared__ float4 sm[NTHR / 64];
    const int lane = threadIdx.x & 63;
    const int wid  = threadIdx.x >> 6;
    if (lane == 0) sm[wid] = make_float4(v0, v1, v2, v3);
    __syncthreads();

    if (threadIdx.x == 0) {
        float4 acc = sm[0];
        #pragma unroll
        for (int w = 1; w < NTHR / 64; ++w) {
            acc.x += sm[w].x; acc.y += sm[w].y;
            acc.z += sm[w].z; acc.w += sm[w].w;
        }
        const float total_all_t   = acc.x;
        const float total_all_s   = acc.y;
        const float total_intra_t = acc.z;
        const float total_intra_s = acc.w;
        const float total_inter_t = total_all_t - total_intra_t;
        const float total_inter_s = total_all_s - total_intra_s;

        int sum_Ms_sq = 0;
        #pragma unroll
        for (int v = 0; v < 4; ++v) sum_Ms_sq += Ms[v] * Ms[v];
        const float diag_count    = (float)((long long)sum_Ms_sq * B_);
        const float offdiag_count = (float)(((long long)M_ * M_ - sum_Ms_sq) * B_);

        const float li_t = (diag_count    > EPS) ? total_intra_t / diag_count    : 0.f;
        const float le_t = (offdiag_count > EPS) ? total_inter_t / offdiag_count : 0.f;
        const float li_s = (diag_count    > EPS) ? total_intra_s / diag_count    : 0.f;
        const float le_s = (offdiag_count > EPS) ? total_inter_s / offdiag_count : 0.f;

        const float loss_t = ALPHA_T  * le_t + (1.f - ALPHA_T)  * li_t;
        const float loss_s = ALPHA_S  * le_s + (1.f - ALPHA_S)  * li_s;
        const float loss   = ALPHA_TS * loss_t + (1.f - ALPHA_TS) * loss_s;

        out[0] = li_t;
        out[1] = le_t;
        out[2] = li_s;
        out[3] = le_s;
        out[4] = loss_t;
        out[5] = loss_s;
        out[6] = loss;
    }
}

extern "C" void kernel_launch(void* const* d_in, const int* in_sizes, int n_in,
                              void* d_out, int out_size, void* d_ws, size_t ws_size,
                              hipStream_t stream) {
    const float4* pred = (const float4*)d_in[0];
    const float4* gt   = (const float4*)d_in[1];
    const int*    Ms   = (const int*)d_in[2];
    float*        out  = (float*)d_out;
    float4*       partials = (float4*)d_ws;   // NBLK * 16 bytes = 28 KB

    pose_loss_partial_kernel<<<NBLK, NTHR, 0, stream>>>(pred, gt, Ms, partials);
    pose_loss_final_kernel<<<1, NTHR, 0, stream>>>(partials, Ms, out);
}